// Round 9
// baseline (256.067 us; speedup 1.0000x reference)
//
#include <hip/hip_runtime.h>

#define BB 8
#define HH 1024
#define WW 1280
#define HW (HH * WW)
#define EPSF 1e-7f

#define TH 16                    // output rows per tile
#define TCOLS 264                // staged cols: global [x0-4 .. x0+259]
#define SROWS 18                 // staged rows: y0-1 .. y0+16
#define CPR 66                   // float4 chunks per staged row
#define CCH (SROWS * CPR)        // 1188 chunks per channel window
#define CPT 5                    // chunks per thread (5*256 = 1280, padded)
#define STF (CPT * 256 * 4)      // 5120 floats = 20480 B LDS (incl. pad)

#define GAS __attribute__((address_space(1)))
#define LAS __attribute__((address_space(3)))

__device__ __forceinline__ float fast_rcp(float x) {
    float r = __builtin_amdgcn_rcpf(x);
    r = r * __builtin_fmaf(-x, r, 2.0f);   // one NR step -> ~1 ulp
    return r;
}

// Per-batch constant folding (8 floats per batch).
__global__ void precompute_consts(
    const float* __restrict__ srcK, const float* __restrict__ tgtK,
    const float* __restrict__ trans, float* __restrict__ cb)
{
    const int b = threadIdx.x;
    if (b >= BB) return;
    const float* sK = srcK + b * 16;
    const float* tK = tgtK + b * 16;
    const float* tv = trans + b * 3;

    const float fsx = sK[0], csx = sK[2];
    const float fsy = sK[5], csy = sK[6];
    const float ftx = tK[0], ctx = tK[2];
    const float fty = tK[5], cty = tK[6];
    const float t0 = tv[0], t1 = tv[1], t2 = tv[2];

    // px = (A00*x + A02 + C0*sd) / (1 + (t2+eps)*sd); sx = px*W/(W-1) - 0.5
    const float Sx = (float)WW / (float)(WW - 1);
    const float Sy = (float)HH / (float)(HH - 1);
    const float rfsx = 1.0f / fsx;
    const float rfsy = 1.0f / fsy;
    float* c = cb + b * 8;
    c[0] = ftx * rfsx * Sx;                                    // A00
    c[1] = __builtin_fmaf(-ftx * csx, rfsx, ctx) * Sx;         // A02
    c[2] = (ftx * t0 + ctx * t2) * Sx;                         // C0
    c[3] = fty * rfsy * Sy;                                    // A11
    c[4] = __builtin_fmaf(-fty * csy, rfsy, cty) * Sy;         // A12
    c[5] = (fty * t1 + cty * t2) * Sy;                         // C1
    c[6] = t2 + EPSF;                                          // t2e
    c[7] = 0.0f;
}

// One CHANNEL per block: stage once, ONE barrier, compute, exit.
// R8's 3-phase channel loop (barrier+vmcnt(0) drain x3 per block) killed
// concurrency (occ 34%, BW 2.5 TB/s). Short independent blocks restore the
// deep block queue that made R2/R5 sustain 3.6-4.4 TB/s.
__global__ __launch_bounds__(256, 4) void synth_view_kernel(
    const float* __restrict__ img, const float* __restrict__ disp,
    const float* __restrict__ cbuf, float* __restrict__ out)
{
    // 256x16 tile; this block's single channel window staged in LDS (20 KB).
    // Footprint bound (fixed K/trans, disp in [0,1)):
    //   sx - x in [-0.91, 0.93], sy - y in [-0.51, 0.61]
    // => window rows y0-1..y0+16, cols x0-1..x0+256 (staged 264, aligned).
    __shared__ __align__(16) float st[STF];

    const int tid = threadIdx.x;
    // wid = c*2560 + t; channel OUTERMOST so each channel-plane dispatches
    // as a contiguous burst (disp tile re-reads hit L3 across planes).
    // Within a plane: XCD-banded decode (XCD = t&7 heuristic) so vertically
    // adjacent tiles share an L2 (2-row stage overlap hits).
    const int wid = blockIdx.x;
    const int c   = wid / 2560;
    const int t   = wid - c * 2560;
    const int r   = t & 7;
    int q = t >> 3;
    const int tyl = q & 7;  q >>= 3;     // q in [0, 40)
    const int xb  = q % 5;
    const int b   = q / 5;
    const int y0  = (r * 8 + tyl) * TH;
    const int x0  = xb * 256;
    const int x   = x0 + tid;

    const float* imc = img + ((size_t)b * 3 + c) * HW;

    // ---- disp loads FIRST (cached, not NT: planes 2,3 re-read them) ----
    const float* db = disp + (size_t)b * HW + (size_t)y0 * WW + x;
    float dsp[TH];
#pragma unroll
    for (int j = 0; j < TH; ++j)
        dsp[j] = db[j * WW];

    // ---- stage this channel's window: 5 direct-to-LDS loads ----
#pragma unroll
    for (int i = 0; i < CPT; ++i) {
        const int qq = i * 256 + tid;
        const int qc = min(qq, CCH - 1);       // pad chunks dup-fetch last
        const int ri = qc / CPR;
        const int k  = qc - ri * CPR;
        const int row = min(max(y0 - 1 + ri, 0), HH - 1);
        const int col = min(max(x0 - 4 + 4 * k, 0), WW - 4);
        __builtin_amdgcn_global_load_lds(
            (const GAS unsigned int*)(const void*)(imc + row * WW + col),
            (LAS unsigned int*)(void*)&st[qq * 4], 16, 0, 0);
    }

    const float* cb = cbuf + b * 8;     // wave-uniform -> scalar loads
    const float A00 = cb[0], A02 = cb[1], C0 = cb[2];
    const float A11 = cb[3], A12 = cb[4], C1 = cb[5];
    const float t2e = cb[6];

    const float mind = 1.0f / 255.0f;
    const float rng  = 0.1f - mind;
    const float axc  = __builtin_fmaf(A00, (float)x, A02);   // row-invariant

    // ---- per-row window byte-offset + bilinear weights ----
    int   lb[TH]; float wxa[TH], wya[TH];
#pragma unroll
    for (int j = 0; j < TH; ++j) {
        const int y = y0 + j;
        const float sd  = __builtin_fmaf(dsp[j], rng, mind);
        const float rrz = fast_rcp(__builtin_fmaf(t2e, sd, 1.0f));
        const float ayc = __builtin_fmaf(A11, (float)y, A12);
        const float sx  = __builtin_fmaf(__builtin_fmaf(C0, sd, axc), rrz, -0.5f);
        const float sy  = __builtin_fmaf(__builtin_fmaf(C1, sd, ayc), rrz, -0.5f);

        // Border-clamp bilinear via weight folding (exact, no selects):
        const int ixc = min(max((int)floorf(sx), 0), WW - 2);
        const int iyc = min(max((int)floorf(sy), 0), HH - 2);
        wxa[j] = fminf(fmaxf(sx - (float)ixc, 0.0f), 1.0f);
        wya[j] = fminf(fmaxf(sy - (float)iyc, 0.0f), 1.0f);
        // window coords; clamps provable no-ops (memory safety only)
        const int wcol = min(max(ixc - x0 + 4, 0), TCOLS - 2);
        const int wrow = min(max(iyc - y0 + 1, 0), SROWS - 2);
        lb[j] = (wrow * TCOLS + wcol) * 4;     // byte offset into window
    }

    __syncthreads();                           // window staged (vmcnt drained)

    float* oc = out + ((size_t)b * 3 + c) * HW + (size_t)y0 * WW + x;
#pragma unroll
    for (int j = 0; j < TH; ++j) {
        const float* p = (const float*)((const char*)st + lb[j]);
        const float wx = wxa[j], wy = wya[j];
        const float wxm = 1.0f - wx, wym = 1.0f - wy;
        float acc =          p[0]         * (wxm * wym);
        acc = __builtin_fmaf(p[1],         wx * wym, acc);
        acc = __builtin_fmaf(p[TCOLS],     wxm * wy, acc);
        acc = __builtin_fmaf(p[TCOLS + 1], wx * wy,  acc);
        __builtin_nontemporal_store(acc, oc + j * WW);
    }
}

extern "C" void kernel_launch(void* const* d_in, const int* in_sizes, int n_in,
                              void* d_out, int out_size, void* d_ws, size_t ws_size,
                              hipStream_t stream) {
    const float* img   = (const float*)d_in[0];
    const float* disp  = (const float*)d_in[1];
    const float* srcK  = (const float*)d_in[2];
    const float* tgtK  = (const float*)d_in[3];
    const float* trans = (const float*)d_in[4];
    float* out = (float*)d_out;
    float* cb  = (float*)d_ws;          // 8 batches x 8 floats = 256 B

    precompute_consts<<<dim3(1), dim3(64), 0, stream>>>(srcK, tgtK, trans, cb);

    dim3 block(256, 1, 1);
    dim3 grid(3 * 5 * 64 * BB, 1, 1);   // 7680 blocks: tile x channel
    synth_view_kernel<<<grid, block, 0, stream>>>(img, disp, cb, out);
}

// Round 10
// 253.698 us; speedup vs baseline: 1.0093x; 1.0093x over previous
//
#include <hip/hip_runtime.h>

#define BB 8
#define HH 1024
#define WW 1280
#define HW (HH * WW)
#define EPSF 1e-7f

#define TCOLS 264               // staged cols: global [x0-4 .. x0+259]
#define CPR   66                // float4 chunks per staged row
#define CCH   (3 * 3 * CPR)     // 594 chunks: 3 ch x 3 rows x 66
#define CHROW (3 * TCOLS)       // 792 floats per channel window

#define GAS __attribute__((address_space(1)))
#define LAS __attribute__((address_space(3)))

__device__ __forceinline__ float fast_rcp(float x) {
    float r = __builtin_amdgcn_rcpf(x);
    r = r * __builtin_fmaf(-x, r, 2.0f);   // one NR step -> ~1 ulp
    return r;
}

// Per-batch constant folding (8 floats per batch).
__global__ void precompute_consts(
    const float* __restrict__ srcK, const float* __restrict__ tgtK,
    const float* __restrict__ trans, float* __restrict__ cb)
{
    const int b = threadIdx.x;
    if (b >= BB) return;
    const float* sK = srcK + b * 16;
    const float* tK = tgtK + b * 16;
    const float* tv = trans + b * 3;

    const float fsx = sK[0], csx = sK[2];
    const float fsy = sK[5], csy = sK[6];
    const float ftx = tK[0], ctx = tK[2];
    const float fty = tK[5], cty = tK[6];
    const float t0 = tv[0], t1 = tv[1], t2 = tv[2];

    // px = (A00*x + A02 + C0*sd) / (1 + (t2+eps)*sd); sx = px*W/(W-1) - 0.5
    const float Sx = (float)WW / (float)(WW - 1);
    const float Sy = (float)HH / (float)(HH - 1);
    const float rfsx = 1.0f / fsx;
    const float rfsy = 1.0f / fsy;
    float* c = cb + b * 8;
    c[0] = ftx * rfsx * Sx;                                    // A00
    c[1] = __builtin_fmaf(-ftx * csx, rfsx, ctx) * Sx;         // A02
    c[2] = (ftx * t0 + ctx * t2) * Sx;                         // C0
    c[3] = fty * rfsy * Sy;                                    // A11
    c[4] = __builtin_fmaf(-fty * csy, rfsy, cty) * Sy;         // A12
    c[5] = (fty * t1 + cty * t2) * Sy;                         // C1
    c[6] = t2 + EPSF;                                          // t2e
    c[7] = 0.0f;
}

// R5's shape (1 output row/block, all 3 channels, high occupancy, proven
// 4.4 TB/s) + y-banded XCD swizzle so the 2/3 staged-row overlap between
// vertically-adjacent blocks hits the XCD's own L2 instead of HBM (R5's
// FETCH=241MB defect). Stage via global_load_lds (zero-VGPR), decode via
// selects (no int div), single barrier per block.
__global__ __launch_bounds__(256) void synth_view_kernel(
    const float* __restrict__ img, const float* __restrict__ disp,
    const float* __restrict__ cbuf, float* __restrict__ out)
{
    // Footprint bound (fixed K/trans, disp in [0,1)):
    //   sx - x in [-0.91, 0.93], sy - y in [-0.51, 0.61]
    // => rows y-1..y+1, cols x0-1..x0+256 (staged 264, 16B-aligned).
    __shared__ __align__(16) float st[768 * 4];   // 594 used + pad = 12288 B

    const int tid = threadIdx.x;
    // y-banded XCD decode (XCD = wid&7 heuristic): XCD r owns rows
    // [128r, 128r+128). Consecutive q walk consecutive rows in one band:
    // rows y+-1 re-staged by neighbor blocks ~15 dispatch-slots apart,
    // working set ~100 KB << 4 MiB L2 -> overlap becomes L2 hits.
    const int wid = blockIdx.x;
    const int r   = wid & 7;
    int q = wid >> 3;                    // [0, 5120)
    const int yl  = q & 127;  q >>= 7;   // row in band; q in [0, 40)
    const int xb  = q % 5;
    const int b   = q / 5;
    const int y   = r * 128 + yl;
    const int x0  = xb * 256;
    const int x   = x0 + tid;

    const float* imb = img + (size_t)b * 3 * HW;

    // ---- disp first (NT, read-once) ----
    const float dsp = __builtin_nontemporal_load(
        disp + (size_t)b * HW + (size_t)y * WW + x);

    // ---- stage 594 f4 chunks, 3 issues/thread, select-based decode ----
    const int ym = min(max(y - 1, 0), HH - 1);   // staged rows: ym? no:
    const int y0c = max(y - 1, 0);               // row 0 of window
    const int y2c = min(y + 1, HH - 1);          // row 2 of window
#pragma unroll
    for (int i = 0; i < 3; ++i) {
        const int qq = i * 256 + tid;            // 0..767
        const int qc = min(qq, CCH - 1);         // pad -> dup-fetch last chunk
        // ch = qc/198, rm = qc%198, row = rm/66, k = rm%66 — via selects
        const int ch = (qc >= 396) ? 2 : ((qc >= 198) ? 1 : 0);
        const int rm = qc - ch * 198;
        const int rw = (rm >= 132) ? 2 : ((rm >= 66) ? 1 : 0);
        const int k  = rm - rw * 66;
        const int row = (rw == 0) ? y0c : ((rw == 1) ? y : y2c);
        const int col = min(max(x0 - 4 + 4 * k, 0), WW - 4);
        __builtin_amdgcn_global_load_lds(
            (const GAS unsigned int*)(const void*)(imb + (size_t)(ch * HH + row) * WW + col),
            (LAS unsigned int*)(void*)&st[qq * 4], 16, 0, 0);
    }
    (void)ym;

    const float* cb = cbuf + b * 8;     // wave-uniform -> scalar loads
    const float A00 = cb[0], A02 = cb[1], C0 = cb[2];
    const float A11 = cb[3], A12 = cb[4], C1 = cb[5];
    const float t2e = cb[6];

    const float mind = 1.0f / 255.0f;
    const float rng  = 0.1f - mind;
    const float sd   = __builtin_fmaf(dsp, rng, mind);
    const float rrz  = fast_rcp(__builtin_fmaf(t2e, sd, 1.0f));
    const float axc  = __builtin_fmaf(A00, (float)x, A02);
    const float ayc  = __builtin_fmaf(A11, (float)y, A12);
    const float sx   = __builtin_fmaf(__builtin_fmaf(C0, sd, axc), rrz, -0.5f);
    const float sy   = __builtin_fmaf(__builtin_fmaf(C1, sd, ayc), rrz, -0.5f);

    // Border-clamp bilinear via weight folding (exact, no selects):
    const int ixc = min(max((int)floorf(sx), 0), WW - 2);
    const int iyc = min(max((int)floorf(sy), 0), HH - 2);
    const float wx = fminf(fmaxf(sx - (float)ixc, 0.0f), 1.0f);
    const float wy = fminf(fmaxf(sy - (float)iyc, 0.0f), 1.0f);

    // window coords; clamps provable no-ops (memory safety only)
    const int wcol = min(max(ixc - x0 + 4, 0), TCOLS - 2);
    const int wrow = min(max(iyc - y + 1, 0), 1);
    const int base = wrow * TCOLS + wcol;

    const float wxm = 1.0f - wx, wym = 1.0f - wy;
    const float w00 = wxm * wym, w01 = wx * wym;
    const float w10 = wxm * wy,  w11 = wx * wy;

    __syncthreads();                     // stage complete (vmcnt drained)

    float* outb = out + (size_t)b * 3 * HW + (size_t)y * WW + x;
#pragma unroll
    for (int c = 0; c < 3; ++c) {
        const float* p = &st[c * CHROW + base];
        float acc =          p[0]          * w00;
        acc = __builtin_fmaf(p[1],          w01, acc);
        acc = __builtin_fmaf(p[TCOLS],      w10, acc);
        acc = __builtin_fmaf(p[TCOLS + 1],  w11, acc);
        __builtin_nontemporal_store(acc, outb + (size_t)c * HW);
    }
}

extern "C" void kernel_launch(void* const* d_in, const int* in_sizes, int n_in,
                              void* d_out, int out_size, void* d_ws, size_t ws_size,
                              hipStream_t stream) {
    const float* img   = (const float*)d_in[0];
    const float* disp  = (const float*)d_in[1];
    const float* srcK  = (const float*)d_in[2];
    const float* tgtK  = (const float*)d_in[3];
    const float* trans = (const float*)d_in[4];
    float* out = (float*)d_out;
    float* cb  = (float*)d_ws;          // 8 batches x 8 floats = 256 B

    precompute_consts<<<dim3(1), dim3(64), 0, stream>>>(srcK, tgtK, trans, cb);

    dim3 block(256, 1, 1);
    dim3 grid(5 * 1024 * BB, 1, 1);     // 40960 blocks: 1 row-chunk each
    synth_view_kernel<<<grid, block, 0, stream>>>(img, disp, cb, out);
}